// Round 11
// baseline (2617.354 us; speedup 1.0000x reference)
//
#include <hip/hip_runtime.h>

// snn_layer: out[b,u,t] = (sum_f in[b,f,t] * w[f,u] > 1.0f) ? 1.0f : 0.0f
// B=128 F=512 T=256 U=1024, fp32 in/out.
//
// fp32 has no MFMA on CDNA4 -> exact bf16 hi/lo split, 3-pass MFMA:
//   h ~= Ah*Bh + Ah*Bl + Al*Bh   (error ~1e-5; threshold band |h-1|<=1e-3
// recomputed in fp32 with the verified sequential-fmaf order -> flip-free).
//
// Round-11: structural rewrite. R2..R10 bracketed the 2048-block/128^2-tile
// structure at 327-500us: every K-chunk pays a barrier-serialized
// global->LDS round trip, and operands are duplicated across blocks
// (X panel staged by 8 blocks, W strip by 256). New structure:
//  * block = (b, t-quarter 64), 512 threads = 8 waves (2/SIMD).
//    LDS = the block's ENTIRE X operand: [64t][512f] hi+lo bf16 = 128 KB,
//    XOR-swizzled segs (seg = fseg ^ row) for conflict-free b128 reads.
//  * Prologue loads X fp32 straight from `in` (coalesced 256B rows),
//    splits hi/lo in-register, ds_writes -> the X half of the prepass is
//    DELETED (-130MB HBM, -~100us). X has zero cross-block duplication.
//    ONE __syncthreads in the whole kernel.
//  * K-loop: A-fragments read directly from the 2MB wth/wtl (all blocks
//    stream it in the same order -> L2/L3-resident), B-fragments from
//    LDS. Zero barriers -> 2 waves/SIMD overlap loads under MFMAs.
//  * Fragment bytes + MFMA order bit-identical to verified rounds
//    (same bf16rn split, same k-seg bytes, hh/hl/lh chunks ascending)
//    -> absmax 0.0 preserved. Band-recompute epilogue unchanged.
//  * W prepass shrinks to a 2MB transpose+split (~5us).

#define BB 128
#define FF 512
#define TT 256
#define UU 1024

typedef float v4f __attribute__((ext_vector_type(4)));
typedef short v8s __attribute__((ext_vector_type(8)));
typedef unsigned short v8us __attribute__((ext_vector_type(8)));

__device__ __forceinline__ unsigned short bf16rn(float x) {
    unsigned u = __float_as_uint(x);
    u = u + 0x7FFFu + ((u >> 16) & 1u);   // round-to-nearest-even
    return (unsigned short)(u >> 16);
}
__device__ __forceinline__ float bf16tof(unsigned short h) {
    return __uint_as_float(((unsigned)h) << 16);
}

// ---------------------------------------------------------------------------
// W prepass: transpose + hi/lo split of W[f][u] -> wT[u][f] (2 MB total).
// Same verified body as before, W branch only. Grid (4 col-tiles, 8 f-tiles,
// 4 u-strips of 256).
// ---------------------------------------------------------------------------
__global__ __launch_bounds__(256)
void wprep_kernel(const float* __restrict__ w,
                  unsigned short* __restrict__ wth, unsigned short* __restrict__ wtl) {
    __shared__ float Ls[64][65];

    const int s = blockIdx.z;
    const float* src = w + s * 256;
    unsigned short* dh = wth + (size_t)s * 256 * FF;
    unsigned short* dl = wtl + (size_t)s * 256 * FF;
    const int f0 = blockIdx.y * 64;
    const int c0 = blockIdx.x * 64;
    const int tid = threadIdx.x;
    const int r  = tid >> 4;
    const int c4 = (tid & 15) * 4;

#pragma unroll
    for (int i = 0; i < 4; i++) {
        const float4 v = *(const float4*)&src[(size_t)(f0 + r + 16 * i) * UU + c0 + c4];
        Ls[r + 16 * i][c4 + 0] = v.x;
        Ls[r + 16 * i][c4 + 1] = v.y;
        Ls[r + 16 * i][c4 + 2] = v.z;
        Ls[r + 16 * i][c4 + 3] = v.w;
    }
    __syncthreads();

#pragma unroll
    for (int i = 0; i < 2; i++) {
        const int orow = 32 * i + (tid >> 3);
        const int fs   = (tid & 7) * 8;
        v8us hp, lp;
#pragma unroll
        for (int k = 0; k < 8; k++) {
            const float a = Ls[fs + k][orow];
            const unsigned short h = bf16rn(a);
            hp[k] = h;
            lp[k] = bf16rn(a - bf16tof(h));
        }
        const size_t o = (size_t)(c0 + orow) * FF + f0 + fs;
        *(v8us*)&dh[o] = hp;
        *(v8us*)&dl[o] = lp;
    }
}

// ---------------------------------------------------------------------------
// Main kernel. 512 blocks = 128 b x 4 t-quarters. 512 threads = 8 waves.
// LDS (dynamic 128 KB): Xh [64t][512f] ++ Xl [64t][512f], seg-XOR-swizzled.
// Each wave computes 2 u-strips of 64 (it*8+wv), acc 4x4 frags, K=512 in
// 16 chunks of 32. A-frags from global (L2-hot W), B-frags from LDS.
// ---------------------------------------------------------------------------
__global__ __launch_bounds__(512, 1)
void snn_mfma_kernel(const unsigned short* __restrict__ wth,
                     const unsigned short* __restrict__ wtl,
                     const float* __restrict__ in, const float* __restrict__ w,
                     float* __restrict__ out) {
    extern __shared__ unsigned short Xs[];     // 128 KB
    unsigned short* Xh = Xs;                   // [64][512]
    unsigned short* Xl = Xs + 64 * 512;        // [64][512]

    const int blk = blockIdx.x;
    const int b   = blk >> 2;
    const int tq  = blk & 3;
    const int t0g = tq * 64;

    const int tid = threadIdx.x;
    const int wv  = tid >> 6;      // wave 0..7
    const int ln  = tid & 63;
    const int lr  = ln & 15;       // fragment m/n index
    const int lq  = ln >> 4;       // fragment k-quad

    // ---- prologue: in-kernel transpose + hi/lo split of the X tile ----
    // thread (fbq = wv, tl = ln): for fb in {fbq, fbq+8, ...}: load 8
    // consecutive f at column tl (each load coalesced: 64 lanes = 256 B),
    // split, store 16B at row tl, seg (fb ^ tl)  [XOR swizzle].
    {
        const float* xsrc = in + (size_t)b * FF * TT + t0g;
#pragma unroll 1
        for (int fb = wv; fb < 64; fb += 8) {
            float v[8];
#pragma unroll
            for (int k = 0; k < 8; k++)
                v[k] = xsrc[(size_t)(fb * 8 + k) * TT + ln];
            v8us hp, lp;
#pragma unroll
            for (int k = 0; k < 8; k++) {
                const unsigned short hh = bf16rn(v[k]);
                hp[k] = hh;
                lp[k] = bf16rn(v[k] - bf16tof(hh));
            }
            const int sseg = (fb ^ ln) & 63;
            *(v8us*)&Xh[ln * 512 + sseg * 8] = hp;
            *(v8us*)&Xl[ln * 512 + sseg * 8] = lp;
        }
    }
    __syncthreads();   // the only barrier in the kernel

    const float* xb   = in  + (size_t)b * FF * TT;
    float* __restrict__ outb = out + (size_t)b * UU * TT;

#pragma unroll 1
    for (int it = 0; it < 2; it++) {
        const int us = (it * 8 + wv) * 64;   // this wave's u-strip

        v4f acc[4][4];
#pragma unroll
        for (int i = 0; i < 4; i++)
#pragma unroll
            for (int j = 0; j < 4; j++) {
                v4f zz = {0.0f, 0.0f, 0.0f, 0.0f};
                acc[i][j] = zz;
            }

        const unsigned short* aph = wth + (size_t)(us + lr) * FF + lq * 8;
        const unsigned short* apl = wtl + (size_t)(us + lr) * FF + lq * 8;

#pragma unroll
        for (int c = 0; c < 16; c++) {
            v8s ah[4], al[4], bh[4], bl[4];
#pragma unroll
            for (int i = 0; i < 4; i++) {
                ah[i] = *(const v8s*)&aph[i * 16 * FF + c * 32];
                al[i] = *(const v8s*)&apl[i * 16 * FF + c * 32];
            }
#pragma unroll
            for (int j = 0; j < 4; j++) {
                const int r = j * 16 + lr;
                const int sseg = ((c * 4 + lq) ^ r) & 63;
                bh[j] = *(const v8s*)&Xh[r * 512 + sseg * 8];
                bl[j] = *(const v8s*)&Xl[r * 512 + sseg * 8];
            }
#pragma unroll
            for (int i = 0; i < 4; i++)
#pragma unroll
                for (int j = 0; j < 4; j++) {
                    acc[i][j] = __builtin_amdgcn_mfma_f32_16x16x32_bf16(ah[i], bh[j], acc[i][j], 0, 0, 0);
                    acc[i][j] = __builtin_amdgcn_mfma_f32_16x16x32_bf16(ah[i], bl[j], acc[i][j], 0, 0, 0);
                    acc[i][j] = __builtin_amdgcn_mfma_f32_16x16x32_bf16(al[i], bh[j], acc[i][j], 0, 0, 0);
                }
        }

        // Epilogue for this u-strip. C/D layout: col=lane&15, row=(lane>>4)*4+reg.
#pragma unroll
        for (int i = 0; i < 4; i++) {
#pragma unroll
            for (int r = 0; r < 4; r++) {
                const int u = us + i * 16 + lq * 4 + r;
#pragma unroll
                for (int j = 0; j < 4; j++) {
                    const int t = t0g + j * 16 + lr;
                    float hh = acc[i][j][r];
                    if (__builtin_expect(__builtin_fabsf(hh - 1.0f) <= 1e-3f, 0)) {
                        // exact fp32 recompute: identical sequential fmaf
                        // order (f ascending) as the verified fp32 kernel.
                        float s2 = 0.0f;
                        const float* wp = w  + u;
                        const float* xp = xb + t;
#pragma unroll 16
                        for (int f = 0; f < FF; f++)
                            s2 = fmaf(wp[(size_t)f * UU], xp[(size_t)f * TT], s2);
                        hh = s2;
                    }
                    outb[(size_t)u * TT + t] = hh > 1.0f ? 1.0f : 0.0f;
                }
            }
        }
    }
}

// ---------------------------------------------------------------------------
// Fallback: previous verified fp32 vector-FMA kernel (used if ws too small).
// ---------------------------------------------------------------------------
__global__ __launch_bounds__(256, 4)
void snn_gemm_kernel(const float* __restrict__ in, const float* __restrict__ w,
                     float* __restrict__ out) {
    __shared__ float As[16][128];
    __shared__ float Bs[16][128];

    const int b  = blockIdx.z;
    const int u0 = blockIdx.y * 128;
    const int t0 = blockIdx.x * 128;

    const float* __restrict__ inb  = in  + (size_t)b * FF * TT;
    float* __restrict__       outb = out + (size_t)b * UU * TT;

    const int tid = threadIdx.x;
    const int tx  = tid & 15;
    const int ty  = tid >> 4;

    const int k0 = tid >> 5;
    const int c0 = (tid & 31) * 4;
    const int k1 = k0 + 8;

    float acc[8][8];
#pragma unroll
    for (int i = 0; i < 8; i++)
#pragma unroll
        for (int j = 0; j < 8; j++) acc[i][j] = 0.0f;

    float4 a_r0 = *(const float4*)&w[(size_t)k0 * UU + u0 + c0];
    float4 a_r1 = *(const float4*)&w[(size_t)k1 * UU + u0 + c0];
    float4 b_r0 = *(const float4*)&inb[k0 * TT + t0 + c0];
    float4 b_r1 = *(const float4*)&inb[k1 * TT + t0 + c0];

    for (int f0 = 0; f0 < FF; f0 += 16) {
        *(float4*)&As[k0][c0] = a_r0;
        *(float4*)&As[k1][c0] = a_r1;
        *(float4*)&Bs[k0][c0] = b_r0;
        *(float4*)&Bs[k1][c0] = b_r1;
        __syncthreads();

        if (f0 + 16 < FF) {
            const int fn = f0 + 16;
            a_r0 = *(const float4*)&w[(size_t)(fn + k0) * UU + u0 + c0];
            a_r1 = *(const float4*)&w[(size_t)(fn + k1) * UU + u0 + c0];
            b_r0 = *(const float4*)&inb[(fn + k0) * TT + t0 + c0];
            b_r1 = *(const float4*)&inb[(fn + k1) * TT + t0 + c0];
        }

#pragma unroll
        for (int k = 0; k < 16; k++) {
            const float4 a0 = *(const float4*)&As[k][ty * 4];
            const float4 a1 = *(const float4*)&As[k][ty * 4 + 64];
            const float4 v0 = *(const float4*)&Bs[k][tx * 4];
            const float4 v1 = *(const float4*)&Bs[k][tx * 4 + 64];
            const float am[8] = {a0.x, a0.y, a0.z, a0.w, a1.x, a1.y, a1.z, a1.w};
            const float bn[8] = {v0.x, v0.y, v0.z, v0.w, v1.x, v1.y, v1.z, v1.w};
#pragma unroll
            for (int i = 0; i < 8; i++)
#pragma unroll
                for (int j = 0; j < 8; j++)
                    acc[i][j] = fmaf(am[i], bn[j], acc[i][j]);
        }
        __syncthreads();
    }

#pragma unroll
    for (int i = 0; i < 8; i++) {
        const int m = (i < 4) ? (ty * 4 + i) : (64 + ty * 4 + i - 4);
        float* __restrict__ orow = outb + (size_t)(u0 + m) * TT + t0;
        float4 o0, o1;
        o0.x = acc[i][0] > 1.0f ? 1.0f : 0.0f;
        o0.y = acc[i][1] > 1.0f ? 1.0f : 0.0f;
        o0.z = acc[i][2] > 1.0f ? 1.0f : 0.0f;
        o0.w = acc[i][3] > 1.0f ? 1.0f : 0.0f;
        o1.x = acc[i][4] > 1.0f ? 1.0f : 0.0f;
        o1.y = acc[i][5] > 1.0f ? 1.0f : 0.0f;
        o1.z = acc[i][6] > 1.0f ? 1.0f : 0.0f;
        o1.w = acc[i][7] > 1.0f ? 1.0f : 0.0f;
        *(float4*)&orow[tx * 4]      = o0;
        *(float4*)&orow[tx * 4 + 64] = o1;
    }
}

extern "C" void kernel_launch(void* const* d_in, const int* in_sizes, int n_in,
                              void* d_out, int out_size, void* d_ws, size_t ws_size,
                              hipStream_t stream) {
    const float* in = (const float*)d_in[0];  // [128,512,256]
    const float* w  = (const float*)d_in[1];  // [512,1024]
    float* out      = (float*)d_out;          // [128,1024,256]

    const size_t WN   = (size_t)UU * FF;                       // 524288 elems
    const size_t NEED = 2 * WN * sizeof(unsigned short);       // 2 MB

    if (ws_size >= NEED) {
        unsigned short* wth = (unsigned short*)d_ws;
        unsigned short* wtl = wth + WN;

        static bool attr_done = false;
        if (!attr_done) {
            (void)hipFuncSetAttribute(
                reinterpret_cast<const void*>(snn_mfma_kernel),
                hipFuncAttributeMaxDynamicSharedMemorySize, 131072);
            attr_done = true;
        }

        wprep_kernel<<<dim3(4, 8, 4), dim3(256), 0, stream>>>(w, wth, wtl);
        snn_mfma_kernel<<<dim3(512), dim3(512), 131072, stream>>>(
            wth, wtl, in, w, out);
    } else {
        snn_gemm_kernel<<<dim3(TT / 128, UU / 128, BB), dim3(256), 0, stream>>>(in, w, out);
    }
}

// Round 12
// 504.318 us; speedup vs baseline: 5.1899x; 5.1899x over previous
//
#include <hip/hip_runtime.h>

// snn_layer: out[b,u,t] = (sum_f in[b,f,t] * w[f,u] > 1.0f) ? 1.0f : 0.0f
// B=128 F=512 T=256 U=1024, fp32 in/out.
//
// fp32 has no MFMA on CDNA4 -> exact bf16 hi/lo split, 3-pass MFMA:
//   h ~= Ah*Bh + Ah*Bl + Al*Bh   (error ~1e-5; threshold band |h-1|<=1e-3
// recomputed in fp32 with the verified sequential-fmaf order -> flip-free).
//
// Round-12 (counter-driven synthesis of R2..R11):
//  * R11's fused/LDS-resident rewrite failed (2500us: every block streamed
//    2MB W past L2 = 953MB FETCH; full-unroll spilled). Reverted to the
//    2048-block/128^2 family.
//  * Why all GLL variants plateau at ~327us: the compiler cannot
//    disambiguate which global_load_lds feeds which ds_read, so it emits
//    vmcnt(0) before the ds_reads -- waiting on the just-issued prefetch.
//    Every GLL schedule is secretly synchronous (R2=R3=R10).
//  * The schedule PROVEN to overlap on this problem is the fp32 fallback's
//    (66% VALUBusy): global->VGPR loads + ds_write commit. VGPR loads get
//    per-register counted waits; ds_reads wait only on lgkmcnt; the loads
//    ride under ~1100 cyc of MFMA.
//  * R8 tried this and spilled (int4 stg[8] class-type array -> scratch,
//    WRITE 1.18GB). Fix per rule #20: EIGHT NAMED ext_vector registers.
//  * Same LDS bytes / swizzle / MFMA order / epilogue as verified rounds.

#define BB 128
#define FF 512
#define TT 256
#define UU 1024

typedef float v4f __attribute__((ext_vector_type(4)));
typedef int   v4i __attribute__((ext_vector_type(4)));
typedef short v8s __attribute__((ext_vector_type(8)));
typedef unsigned short v8us __attribute__((ext_vector_type(8)));

__device__ __forceinline__ unsigned short bf16rn(float x) {
    unsigned u = __float_as_uint(x);
    u = u + 0x7FFFu + ((u >> 16) & 1u);   // round-to-nearest-even
    return (unsigned short)(u >> 16);
}
__device__ __forceinline__ float bf16tof(unsigned short h) {
    return __uint_as_float(((unsigned)h) << 16);
}

// ---------------------------------------------------------------------------
// Prepass: transpose + hi/lo split (unchanged, verified).
// ---------------------------------------------------------------------------
__global__ __launch_bounds__(256)
void prepass_kernel(const float* __restrict__ in, const float* __restrict__ w,
                    unsigned short* __restrict__ xth, unsigned short* __restrict__ xtl,
                    unsigned short* __restrict__ wth, unsigned short* __restrict__ wtl) {
    __shared__ float Ls[64][65];

    const int z = blockIdx.z;
    const float* src;
    int srow;
    unsigned short *dh, *dl;
    if (z < BB) {
        src = in + (size_t)z * FF * TT;  srow = TT;
        dh = xth + (size_t)z * TT * FF;  dl = xtl + (size_t)z * TT * FF;
    } else {
        const int s = z - BB;
        src = w + s * 256;               srow = UU;
        dh = wth + (size_t)s * 256 * FF; dl = wtl + (size_t)s * 256 * FF;
    }
    const int f0 = blockIdx.y * 64;
    const int c0 = blockIdx.x * 64;
    const int tid = threadIdx.x;
    const int r  = tid >> 4;
    const int c4 = (tid & 15) * 4;

#pragma unroll
    for (int i = 0; i < 4; i++) {
        const float4 v = *(const float4*)&src[(size_t)(f0 + r + 16 * i) * srow + c0 + c4];
        Ls[r + 16 * i][c4 + 0] = v.x;
        Ls[r + 16 * i][c4 + 1] = v.y;
        Ls[r + 16 * i][c4 + 2] = v.z;
        Ls[r + 16 * i][c4 + 3] = v.w;
    }
    __syncthreads();

#pragma unroll
    for (int i = 0; i < 2; i++) {
        const int orow = 32 * i + (tid >> 3);
        const int fs   = (tid & 7) * 8;
        v8us hp, lp;
#pragma unroll
        for (int k = 0; k < 8; k++) {
            const float a = Ls[fs + k][orow];
            const unsigned short h = bf16rn(a);
            hp[k] = h;
            lp[k] = bf16rn(a - bf16tof(h));
        }
        const size_t o = (size_t)(c0 + orow) * FF + f0 + fs;
        *(v8us*)&dh[o] = hp;
        *(v8us*)&dl[o] = lp;
    }
}

// ---------------------------------------------------------------------------
// Main MFMA GEMM. 128x128 tile, BK=32, 4 waves (2x2 of 64x64).
// LDS: single buffer Ah|Al|Bh|Bl, each [128 rows][32 bf16] (8 KB) = 32 KB.
// Staging: global->named VGPRs -> ds_write (fp32-fallback schedule).
// k-segments XOR-permuted at the global source, un-permuted at read.
// ---------------------------------------------------------------------------
__device__ __forceinline__ void compute_chunk(const unsigned short* S, v4f acc[4][4],
                                              int wm, int wn, int lr, int ksel) {
    v8s ah[4], al[4], bh[4], bl[4];
#pragma unroll
    for (int i = 0; i < 4; i++) {
        const int ra = (wm + i * 16 + lr) * 32 + ksel;
        ah[i] = *(const v8s*)&S[ra];
        al[i] = *(const v8s*)&S[4096 + ra];
    }
#pragma unroll
    for (int j = 0; j < 4; j++) {
        const int rb = (wn + j * 16 + lr) * 32 + ksel;
        bh[j] = *(const v8s*)&S[8192 + rb];
        bl[j] = *(const v8s*)&S[12288 + rb];
    }
#pragma unroll
    for (int i = 0; i < 4; i++)
#pragma unroll
        for (int j = 0; j < 4; j++) {
            acc[i][j] = __builtin_amdgcn_mfma_f32_16x16x32_bf16(ah[i], bh[j], acc[i][j], 0, 0, 0);
            acc[i][j] = __builtin_amdgcn_mfma_f32_16x16x32_bf16(ah[i], bl[j], acc[i][j], 0, 0, 0);
            acc[i][j] = __builtin_amdgcn_mfma_f32_16x16x32_bf16(al[i], bh[j], acc[i][j], 0, 0, 0);
        }
}

// load chunk (byte offset fb) into the 8 named staging registers
#define LOADC(fb)                                                             \
    s0 = *(const v4i*)(gbase + (size_t)(0 * 16 + lrow) * 1024 + (fb) + lseg); \
    s1 = *(const v4i*)(gbase + (size_t)(1 * 16 + lrow) * 1024 + (fb) + lseg); \
    s2 = *(const v4i*)(gbase + (size_t)(2 * 16 + lrow) * 1024 + (fb) + lseg); \
    s3 = *(const v4i*)(gbase + (size_t)(3 * 16 + lrow) * 1024 + (fb) + lseg); \
    s4 = *(const v4i*)(gbase + (size_t)(4 * 16 + lrow) * 1024 + (fb) + lseg); \
    s5 = *(const v4i*)(gbase + (size_t)(5 * 16 + lrow) * 1024 + (fb) + lseg); \
    s6 = *(const v4i*)(gbase + (size_t)(6 * 16 + lrow) * 1024 + (fb) + lseg); \
    s7 = *(const v4i*)(gbase + (size_t)(7 * 16 + lrow) * 1024 + (fb) + lseg)

// commit the 8 named staging registers to this wave's LDS tile
#define COMMITC()                                  \
    *(v4i*)(lbase + 0 * 1024 + ln * 16) = s0;      \
    *(v4i*)(lbase + 1 * 1024 + ln * 16) = s1;      \
    *(v4i*)(lbase + 2 * 1024 + ln * 16) = s2;      \
    *(v4i*)(lbase + 3 * 1024 + ln * 16) = s3;      \
    *(v4i*)(lbase + 4 * 1024 + ln * 16) = s4;      \
    *(v4i*)(lbase + 5 * 1024 + ln * 16) = s5;      \
    *(v4i*)(lbase + 6 * 1024 + ln * 16) = s6;      \
    *(v4i*)(lbase + 7 * 1024 + ln * 16) = s7

__global__ __launch_bounds__(256, 2)
void snn_mfma_kernel(const unsigned short* __restrict__ wth,
                     const unsigned short* __restrict__ wtl,
                     const unsigned short* __restrict__ xth,
                     const unsigned short* __restrict__ xtl,
                     const float* __restrict__ in, const float* __restrict__ w,
                     float* __restrict__ out) {
    __shared__ unsigned short smem[4 * 128 * 32];  // Ah | Al | Bh | Bl, 32 KB

    // XCD-chunked, b-major swizzle (proven: FETCH 507->390 MB).
    const int h = blockIdx.x;
    const int l = ((h & 7) << 8) | (h >> 3);
    const int b  = l >> 4;
    const int u0 = ((l >> 1) & 7) * 128;
    const int t0 = (l & 1) * 128;

    const int tid = threadIdx.x;
    const int wv  = tid >> 6;        // wave 0..3
    const int ln  = tid & 63;
    const int lr  = ln & 15;         // fragment m/n index
    const int lq  = ln >> 4;         // fragment k-quad
    const int wm  = (wv & 1) * 64;   // wave tile origin (u)
    const int wn  = (wv >> 1) * 64;  // wave tile origin (t)

    // staging source for this wave; all sources have 1024-B rows
    const char* gbase;
    if      (wv == 0) gbase = (const char*)wth + (size_t)u0 * (FF * 2);
    else if (wv == 1) gbase = (const char*)wtl + (size_t)u0 * (FF * 2);
    else if (wv == 2) gbase = (const char*)xth + ((size_t)b * TT + t0) * (FF * 2);
    else              gbase = (const char*)xtl + ((size_t)b * TT + t0) * (FF * 2);
    const int lrow = ln >> 2;                               // row within 16-row slab
    const int lseg = (((ln & 3) ^ ((lrow >> 1) & 3)) * 16); // XOR-swizzled source seg

    char* lbase = (char*)&smem[wv * 4096];  // this wave's 8 KB tile (linear dest)

    v4f acc[4][4];
#pragma unroll
    for (int i = 0; i < 4; i++)
#pragma unroll
        for (int j = 0; j < 4; j++) {
            v4f zz = {0.0f, 0.0f, 0.0f, 0.0f};
            acc[i][j] = zz;
        }

    // read-side segment select: same involution as the staged source
    const int ksel = (lq ^ ((lr >> 1) & 3)) * 8;

    // --- fp32-fallback schedule: commit; barrier; load next; compute; barrier
    v4i s0, s1, s2, s3, s4, s5, s6, s7;     // named staging regs (no arrays!)
    LOADC(0);                               // prologue: chunk 0 -> regs

#pragma unroll 1
    for (int c = 0; c < 16; c++) {
        COMMITC();                          // regs -> LDS (8 ds_write_b128)
        __syncthreads();                    // chunk c visible to all waves

        if (c + 1 < 16) { LOADC((c + 1) * 64); }  // prefetch under compute

        compute_chunk(smem, acc, wm, wn, lr, ksel);
        __syncthreads();                    // all waves done reading chunk c
    }

    // Epilogue. C/D layout: col = lane&15, row = (lane>>4)*4+reg.
    const float* xb   = in  + (size_t)b * FF * TT;
    float* __restrict__ outb = out + (size_t)b * UU * TT;
#pragma unroll
    for (int i = 0; i < 4; i++) {
#pragma unroll
        for (int r = 0; r < 4; r++) {
            const int u = u0 + wm + i * 16 + lq * 4 + r;
#pragma unroll
            for (int j = 0; j < 4; j++) {
                const int t = t0 + wn + j * 16 + lr;
                float hh = acc[i][j][r];
                if (__builtin_expect(__builtin_fabsf(hh - 1.0f) <= 1e-3f, 0)) {
                    // exact fp32 recompute: identical sequential fmaf order
                    // (f ascending from 0) as the verified fp32 kernel.
                    float s2 = 0.0f;
                    const float* wp = w  + u;
                    const float* xp = xb + t;
#pragma unroll 16
                    for (int f = 0; f < FF; f++)
                        s2 = fmaf(wp[(size_t)f * UU], xp[(size_t)f * TT], s2);
                    hh = s2;
                }
                outb[(size_t)u * TT + t] = hh > 1.0f ? 1.0f : 0.0f;
            }
        }
    }
}

// ---------------------------------------------------------------------------
// Fallback: previous verified fp32 vector-FMA kernel (used if ws too small).
// ---------------------------------------------------------------------------
__global__ __launch_bounds__(256, 4)
void snn_gemm_kernel(const float* __restrict__ in, const float* __restrict__ w,
                     float* __restrict__ out) {
    __shared__ float As[16][128];
    __shared__ float Bs[16][128];

    const int b  = blockIdx.z;
    const int u0 = blockIdx.y * 128;
    const int t0 = blockIdx.x * 128;

    const float* __restrict__ inb  = in  + (size_t)b * FF * TT;
    float* __restrict__       outb = out + (size_t)b * UU * TT;

    const int tid = threadIdx.x;
    const int tx  = tid & 15;
    const int ty  = tid >> 4;

    const int k0 = tid >> 5;
    const int c0 = (tid & 31) * 4;
    const int k1 = k0 + 8;

    float acc[8][8];
#pragma unroll
    for (int i = 0; i < 8; i++)
#pragma unroll
        for (int j = 0; j < 8; j++) acc[i][j] = 0.0f;

    float4 a_r0 = *(const float4*)&w[(size_t)k0 * UU + u0 + c0];
    float4 a_r1 = *(const float4*)&w[(size_t)k1 * UU + u0 + c0];
    float4 b_r0 = *(const float4*)&inb[k0 * TT + t0 + c0];
    float4 b_r1 = *(const float4*)&inb[k1 * TT + t0 + c0];

    for (int f0 = 0; f0 < FF; f0 += 16) {
        *(float4*)&As[k0][c0] = a_r0;
        *(float4*)&As[k1][c0] = a_r1;
        *(float4*)&Bs[k0][c0] = b_r0;
        *(float4*)&Bs[k1][c0] = b_r1;
        __syncthreads();

        if (f0 + 16 < FF) {
            const int fn = f0 + 16;
            a_r0 = *(const float4*)&w[(size_t)(fn + k0) * UU + u0 + c0];
            a_r1 = *(const float4*)&w[(size_t)(fn + k1) * UU + u0 + c0];
            b_r0 = *(const float4*)&inb[(fn + k0) * TT + t0 + c0];
            b_r1 = *(const float4*)&inb[(fn + k1) * TT + t0 + c0];
        }

#pragma unroll
        for (int k = 0; k < 16; k++) {
            const float4 a0 = *(const float4*)&As[k][ty * 4];
            const float4 a1 = *(const float4*)&As[k][ty * 4 + 64];
            const float4 v0 = *(const float4*)&Bs[k][tx * 4];
            const float4 v1 = *(const float4*)&Bs[k][tx * 4 + 64];
            const float am[8] = {a0.x, a0.y, a0.z, a0.w, a1.x, a1.y, a1.z, a1.w};
            const float bn[8] = {v0.x, v0.y, v0.z, v0.w, v1.x, v1.y, v1.z, v1.w};
#pragma unroll
            for (int i = 0; i < 8; i++)
#pragma unroll
                for (int j = 0; j < 8; j++)
                    acc[i][j] = fmaf(am[i], bn[j], acc[i][j]);
        }
        __syncthreads();
    }

#pragma unroll
    for (int i = 0; i < 8; i++) {
        const int m = (i < 4) ? (ty * 4 + i) : (64 + ty * 4 + i - 4);
        float* __restrict__ orow = outb + (size_t)(u0 + m) * TT + t0;
        float4 o0, o1;
        o0.x = acc[i][0] > 1.0f ? 1.0f : 0.0f;
        o0.y = acc[i][1] > 1.0f ? 1.0f : 0.0f;
        o0.z = acc[i][2] > 1.0f ? 1.0f : 0.0f;
        o0.w = acc[i][3] > 1.0f ? 1.0f : 0.0f;
        o1.x = acc[i][4] > 1.0f ? 1.0f : 0.0f;
        o1.y = acc[i][5] > 1.0f ? 1.0f : 0.0f;
        o1.z = acc[i][6] > 1.0f ? 1.0f : 0.0f;
        o1.w = acc[i][7] > 1.0f ? 1.0f : 0.0f;
        *(float4*)&orow[tx * 4]      = o0;
        *(float4*)&orow[tx * 4 + 64] = o1;
    }
}

extern "C" void kernel_launch(void* const* d_in, const int* in_sizes, int n_in,
                              void* d_out, int out_size, void* d_ws, size_t ws_size,
                              hipStream_t stream) {
    const float* in = (const float*)d_in[0];  // [128,512,256]
    const float* w  = (const float*)d_in[1];  // [512,1024]
    float* out      = (float*)d_out;          // [128,1024,256]

    const size_t XN  = (size_t)BB * TT * FF;
    const size_t WN  = (size_t)UU * FF;
    const size_t NEED = (2 * XN + 2 * WN) * sizeof(unsigned short);

    if (ws_size >= NEED) {
        unsigned short* xth = (unsigned short*)d_ws;
        unsigned short* xtl = xth + XN;
        unsigned short* wth = xtl + XN;
        unsigned short* wtl = wth + WN;
        prepass_kernel<<<dim3(4, 8, 132), dim3(256), 0, stream>>>(in, w, xth, xtl, wth, wtl);
        snn_mfma_kernel<<<dim3(2048), dim3(256), 0, stream>>>(
            wth, wtl, xth, xtl, in, w, out);
    } else {
        snn_gemm_kernel<<<dim3(TT / 128, UU / 128, BB), dim3(256), 0, stream>>>(in, w, out);
    }
}